// Round 18
// baseline (306.902 us; speedup 1.0000x reference)
//
#include <hip/hip_runtime.h>
#include <hip/hip_bf16.h>
#include <cstdint>

#define NODES 50000
#define EDGES 400000
#define FIN   988
#define KP    1024     // FIN padded to multiple of 64
#define FH    256
#define FC    47

typedef __attribute__((ext_vector_type(8))) short short8;
typedef __attribute__((ext_vector_type(4))) float f32x4;

__device__ __forceinline__ ushort f2bf(float x) {      // RNE f32 -> bf16
    union { float f; uint32_t u; } v; v.f = x;
    uint32_t r = v.u + 0x7FFF + ((v.u >> 16) & 1);
    return (ushort)(r >> 16);
}
__device__ __forceinline__ float bf2f(ushort u) {
    union { uint32_t u; float f; } v; v.u = ((uint32_t)u) << 16;
    return v.f;
}
__device__ __forceinline__ void g2l16(const void* g, void* l) {
    __builtin_amdgcn_global_load_lds((const __attribute__((address_space(1))) void*)g,
                                     (__attribute__((address_space(3))) void*)l, 16, 0, 0);
}

// ---------------- CSR build (parallel) ----------------
__global__ void k_zero(int* __restrict__ p, int n) {
    int i = blockIdx.x * blockDim.x + threadIdx.x;
    if (i < n) p[i] = 0;
}

// fused: blocks [0, CVTX_BLKS) convert x->xbf (BW-bound);
//        blocks [CVTX_BLKS, ..) count degrees (atomic-bound). Disjoint writes.
#define CVTX_BLKS (NODES * (KP / 8) / 256)          // 25000
#define DEG_BLKS  ((EDGES + 255) / 256)             // 1563
__global__ void k_cvtx_deg(const float* __restrict__ x, ushort* __restrict__ xbf,
                           const int* __restrict__ dst, int* __restrict__ deg) {
    const int b = blockIdx.x;
    if (b < CVTX_BLKS) {
        int gid = b * 256 + threadIdx.x;
        const int r  = gid >> 7;            // KP/8 = 128
        const int kb = (gid & 127) << 3;
        const float* p = x + (size_t)r * FIN + kb;
        short8 o;
        if (kb + 8 <= FIN) {
            f32x4 v0 = *(const f32x4*)(p);
            f32x4 v1 = *(const f32x4*)(p + 4);
#pragma unroll
            for (int i = 0; i < 4; ++i) {
                o[i] = (short)f2bf(v0[i]);
                o[4 + i] = (short)f2bf(v1[i]);
            }
        } else {
#pragma unroll
            for (int i = 0; i < 8; ++i) {
                float f = (kb + i < FIN) ? p[i] : 0.f;
                o[i] = (short)f2bf(f);
            }
        }
        *(short8*)&xbf[(size_t)r * KP + kb] = o;
    } else {
        int i = (b - CVTX_BLKS) * 256 + threadIdx.x;
        if (i < EDGES) atomicAdd(&deg[dst[i]], 1);
    }
}

#define W0E (512 * KP)
#define W1E (512 * FH)
#define W2E (128 * FH)
#define CVTW0_BLKS ((W0E + 255) / 256)   // 2048
#define SCAN_BLKS  ((NODES + 255) / 256) // 196

// fused: blocks [0,SCAN_BLKS) per-block degree sums; rest convert Wt0 (indep).
__global__ __launch_bounds__(256) void k_scan1_cvtw0(const int* __restrict__ deg,
                                                     int* __restrict__ bsum, int n,
                                                     const float* __restrict__ Ws0,
                                                     const float* __restrict__ Wn0,
                                                     ushort* __restrict__ Wt0) {
    const int b = blockIdx.x;
    if (b < SCAN_BLKS) {
        __shared__ int ws[4];
        int i = b * 256 + threadIdx.x;
        int v = (i < n) ? deg[i] : 0;
#pragma unroll
        for (int off = 32; off; off >>= 1) v += __shfl_down(v, off);
        if ((threadIdx.x & 63) == 0) ws[threadIdx.x >> 6] = v;
        __syncthreads();
        if (threadIdx.x == 0) bsum[b] = ws[0] + ws[1] + ws[2] + ws[3];
    } else {
        int gid = (b - SCAN_BLKS) * 256 + threadIdx.x;
        if (gid < W0E) {
            int k = gid >> 9, n2 = gid & 511;
            float v = 0.f;
            if (k < FIN) v = (n2 < FH) ? Ws0[(size_t)k * FH + n2] : Wn0[(size_t)k * FH + (n2 - FH)];
            Wt0[(size_t)n2 * KP + k] = f2bf(v);
        }
    }
}

// pass 2: exclusive scan of bsum[nb] in one block (nb <= 256)
__global__ __launch_bounds__(256) void k_scan2(int* __restrict__ bsum, int nb) {
    __shared__ int s[256];
    int t = threadIdx.x;
    int v = (t < nb) ? bsum[t] : 0;
    s[t] = v;
    __syncthreads();
    for (int off = 1; off < 256; off <<= 1) {
        int u = (t >= off) ? s[t - off] : 0;
        __syncthreads();
        s[t] += u;
        __syncthreads();
    }
    if (t < nb) bsum[t] = s[t] - v;   // exclusive prefix
}

// pass 3: rowptr[i] = bsum[bid] + in-block exclusive scan; cursor[i] = same
__global__ __launch_bounds__(256) void k_scan3(const int* __restrict__ deg,
                                               const int* __restrict__ bsum,
                                               int* __restrict__ rowptr,
                                               int* __restrict__ cursor, int n) {
    __shared__ int s[256];
    int t = threadIdx.x;
    int i = blockIdx.x * 256 + t;
    int v = (i < n) ? deg[i] : 0;
    s[t] = v;
    __syncthreads();
    for (int off = 1; off < 256; off <<= 1) {
        int u = (t >= off) ? s[t - off] : 0;
        __syncthreads();
        s[t] += u;
        __syncthreads();
    }
    if (i < n) {
        int excl = bsum[blockIdx.x] + s[t] - v;
        rowptr[i] = excl;
        cursor[i] = excl;
    }
    if (i == 0) rowptr[n] = EDGES;   // total degree == EDGES by construction
}

// ================= 256x256 bf16 GEMM, BK=64: 2-buffer counted-vmcnt double-buffer =================
// AUX=1 (L0 only): prologue does the eidx bucket-fill + Wt1/Wt2 convert while
// the first two tile-DMAs are in flight; a vmcnt(0) then re-zeroes the counter
// (prologue loads/stores tick vmcnt) so the loop's counted waits stay exact.
// The prologue's outputs (eidx, Wt1, Wt2) are read only by LATER kernels.
#define TBK 16384   // ushorts per 256x64 tile buffer (32 KB)

template<int AUX>
__global__ __launch_bounds__(512, 2) void k_mm256(const ushort* __restrict__ A,
                                                  const ushort* __restrict__ Bt,
                                                  ushort* __restrict__ C,
                                                  const int M, const int lda,
                                                  const int Kpad, const int ldc,
                                                  const int nbx,
                                                  const int* __restrict__ srcp,
                                                  const int* __restrict__ dstp,
                                                  int* __restrict__ cursor,
                                                  int* __restrict__ eidx,
                                                  const float* __restrict__ Ws1,
                                                  const float* __restrict__ Wn1,
                                                  const float* __restrict__ Ws2,
                                                  const float* __restrict__ Wn2,
                                                  ushort* __restrict__ Wt1o,
                                                  ushort* __restrict__ Wt2o) {
    const int nwg = gridDim.x;
    const int bid = blockIdx.x;
    const int q = nwg >> 3, r = nwg & 7;
    const int xcd = bid & 7, ii = bid >> 3;
    const int swz = (xcd < r ? xcd * (q + 1) : r * (q + 1) + (xcd - r) * q) + ii;
    const int bm = (swz / nbx) * 256;
    const int bn = (swz % nbx) * 256;

    __shared__ ushort As[2 * TBK];   // 64 KB
    __shared__ ushort Bs[2 * TBK];   // 64 KB

    const int t = threadIdx.x;
    const int wid = t >> 6, lane = t & 63;
    const int wr = (wid >> 2) * 128, wc = (wid & 3) * 64;
    const int lr = lane & 15, g = lane >> 4;

    f32x4 acc[8][4] = {};

    const ushort* asrc[4]; const ushort* bsrc[4]; int cdst[4];
#pragma unroll
    for (int jj = 0; jj < 4; ++jj) {
        const int c = jj * 8 + wid;
        const int row = c * 8 + (lane >> 3);
        const int soff = ((lane & 7) ^ (row & 7)) << 3;   // source-side slot XOR
        const int arow = min(bm + row, M - 1);
        asrc[jj] = A + (size_t)arow * lda + soff;
        bsrc[jj] = Bt + (size_t)(bn + row) * Kpad + soff;
        cdst[jj] = c * 512;
    }

    int roA[2][8], roB[2][4];
#pragma unroll
    for (int m = 0; m < 8; ++m) {
        const int rr = wr + m * 16 + lr;
#pragma unroll
        for (int h = 0; h < 2; ++h)
            roA[h][m] = rr * 64 + ((((h << 2) + g) ^ (rr & 7)) << 3);
    }
#pragma unroll
    for (int n = 0; n < 4; ++n) {
        const int col = wc + n * 16 + lr;
#pragma unroll
        for (int h = 0; h < 2; ++h)
            roB[h][n] = col * 64 + ((((h << 2) + g) ^ (col & 7)) << 3);
    }

    auto stage = [&](int tile) {
        const int k0 = tile * 64;
        const int ho = (tile & 1) * TBK;
#pragma unroll
        for (int jj = 0; jj < 4; ++jj) g2l16(asrc[jj] + k0, &As[ho + cdst[jj]]);
#pragma unroll
        for (int jj = 0; jj < 4; ++jj) g2l16(bsrc[jj] + k0, &Bs[ho + cdst[jj]]);
    };

    const int nt = Kpad / 64;
    stage(0);
    if (nt > 1) stage(1);

    if constexpr (AUX) {
        // hidden under the in-flight tile-0/1 DMAs (~10us of serial dispatches saved)
        const int rawtid = bid * 512 + t;                 // raw bid: full coverage
        if (rawtid * 2 + 1 < EDGES) {                     // EDGES even -> covers all
            int2 d2 = ((const int2*)dstp)[rawtid];
            int2 s2 = ((const int2*)srcp)[rawtid];
            int p0 = atomicAdd(&cursor[d2.x], 1); eidx[p0] = s2.x;
            int p1 = atomicAdd(&cursor[d2.y], 1); eidx[p1] = s2.y;
        }
        if (rawtid < W1E + W2E) {
            if (rawtid < W1E) {
                int k = rawtid >> 9, n2 = rawtid & 511;
                float v = (n2 < FH) ? Ws1[(size_t)k * FH + n2] : Wn1[(size_t)k * FH + (n2 - FH)];
                Wt1o[(size_t)n2 * FH + k] = f2bf(v);
            } else {
                int gg = rawtid - W1E;
                int k = gg >> 7, n2 = gg & 127;
                float v = 0.f;
                if (n2 < FC) v = Ws2[(size_t)k * FC + n2];
                else if (n2 >= 64 && n2 < 64 + FC) v = Wn2[(size_t)k * FC + (n2 - 64)];
                Wt2o[(size_t)n2 * FH + k] = f2bf(v);
            }
        }
        // re-zero vmcnt: prologue loads/stores tick it; tiles 0/1 drain here too
        asm volatile("s_waitcnt vmcnt(0)" ::: "memory");
    }

    for (int it = 0; it < nt; ++it) {
        if (it + 1 < nt) asm volatile("s_waitcnt vmcnt(8)" ::: "memory");
        else             asm volatile("s_waitcnt vmcnt(0)" ::: "memory");
        __builtin_amdgcn_s_barrier();           // barrier-1: tile `it` resident
        __builtin_amdgcn_sched_barrier(0);

        const ushort* Ab = &As[(it & 1) * TBK];
        const ushort* Bb = &Bs[(it & 1) * TBK];
        short8 a0[8], b0[4], a1[8], b1[4];
#pragma unroll
        for (int m = 0; m < 8; ++m) a0[m] = *(const short8*)&Ab[roA[0][m]];
#pragma unroll
        for (int n = 0; n < 4; ++n) b0[n] = *(const short8*)&Bb[roB[0][n]];
#pragma unroll
        for (int m = 0; m < 8; ++m) a1[m] = *(const short8*)&Ab[roA[1][m]];
#pragma unroll
        for (int n = 0; n < 4; ++n) b1[n] = *(const short8*)&Bb[roB[1][n]];

        __builtin_amdgcn_s_setprio(1);
#pragma unroll
        for (int m = 0; m < 8; ++m)
#pragma unroll
            for (int n = 0; n < 4; ++n)
                acc[m][n] = __builtin_amdgcn_mfma_f32_16x16x32_bf16(a0[m], b0[n], acc[m][n], 0, 0, 0);
        __builtin_amdgcn_s_setprio(0);

        asm volatile("s_waitcnt lgkmcnt(0)" ::: "memory");
        __builtin_amdgcn_sched_barrier(0);
        __builtin_amdgcn_s_barrier();           // barrier-2: buf[it&1] reads done
        __builtin_amdgcn_sched_barrier(0);

        if (it + 2 < nt) stage(it + 2);         // overwrite buf[it&1] under MFMA h1

        __builtin_amdgcn_s_setprio(1);
#pragma unroll
        for (int m = 0; m < 8; ++m)
#pragma unroll
            for (int n = 0; n < 4; ++n)
                acc[m][n] = __builtin_amdgcn_mfma_f32_16x16x32_bf16(a1[m], b1[n], acc[m][n], 0, 0, 0);
        __builtin_amdgcn_s_setprio(0);
    }

#pragma unroll
    for (int m = 0; m < 8; ++m) {
#pragma unroll
        for (int i = 0; i < 4; ++i) {
            const int row = bm + wr + m * 16 + g * 4 + i;
            if (row >= M) continue;
#pragma unroll
            for (int n = 0; n < 4; ++n) {
                const int col = bn + wc + n * 16 + lr;
                C[(size_t)row * ldc + col] = f2bf(acc[m][n][i]);
            }
        }
    }
}

// ================= 128x128 bf16 GEMM — L2 (N=128), BK=32, linear sources =================
#define BMT 128
#define TBUF 4096
#define NBUF 5

__global__ __launch_bounds__(256, 4) void k_mm(const ushort* __restrict__ A,
                                               const ushort* __restrict__ Bt,
                                               ushort* __restrict__ C,
                                               const int M, const int lda,
                                               const int Kpad, const int ldc,
                                               const int nbx) {
    const int nwg = gridDim.x;
    const int bid = blockIdx.x;
    const int q = nwg >> 3, r = nwg & 7;
    const int xcd = bid & 7, ii = bid >> 3;
    const int swz = (xcd < r ? xcd * (q + 1) : r * (q + 1) + (xcd - r) * q) + ii;
    const int bm = (swz / nbx) * BMT;
    const int bn = (swz % nbx) * BMT;

    __shared__ ushort As[NBUF * TBUF];
    __shared__ ushort Bs[NBUF * TBUF];

    const int t = threadIdx.x;
    const int wid = t >> 6, lane = t & 63;
    const int wr = (wid >> 1) * 64, wc = (wid & 1) * 64;
    const int lr = lane & 15, g = lane >> 4;

    f32x4 acc[4][4] = {};

    const ushort* asrc[2]; const ushort* bsrc[2]; int cdst[2];
#pragma unroll
    for (int j = 0; j < 2; ++j) {
        const int c = j * 4 + wid;
        const int row = c * 16 + (lane >> 2);
        const int soff = (((lane & 3) ^ ((row >> 1) & 3)) << 3);  // source-side XOR
        const int arow = min(bm + row, M - 1);
        asrc[j] = A + (size_t)arow * lda + soff;
        bsrc[j] = Bt + (size_t)(bn + row) * Kpad + soff;
        cdst[j] = c * 512;
    }

    int roA[4], roB[4];
#pragma unroll
    for (int m = 0; m < 4; ++m) {
        const int row = wr + m * 16 + lr;
        roA[m] = row * 32 + ((g ^ ((row >> 1) & 3)) << 3);
    }
#pragma unroll
    for (int n = 0; n < 4; ++n) {
        const int col = wc + n * 16 + lr;
        roB[n] = col * 32 + ((g ^ ((col >> 1) & 3)) << 3);
    }

    auto stage = [&](int tile) {
        const int k0 = tile * 32;
        const int ho = (tile % NBUF) * TBUF;
        g2l16(asrc[0] + k0, &As[ho + cdst[0]]);
        g2l16(asrc[1] + k0, &As[ho + cdst[1]]);
        g2l16(bsrc[0] + k0, &Bs[ho + cdst[0]]);
        g2l16(bsrc[1] + k0, &Bs[ho + cdst[1]]);
    };

    const int nt = Kpad / 32;
#pragma unroll
    for (int p = 0; p < 4; ++p) if (p < nt) stage(p);

    for (int it = 0; it < nt; ++it) {
        const int rmn = nt - 1 - it;
        if (rmn >= 3)      asm volatile("s_waitcnt vmcnt(12)" ::: "memory");
        else if (rmn == 2) asm volatile("s_waitcnt vmcnt(8)"  ::: "memory");
        else if (rmn == 1) asm volatile("s_waitcnt vmcnt(4)"  ::: "memory");
        else               asm volatile("s_waitcnt vmcnt(0)"  ::: "memory");
        __builtin_amdgcn_s_barrier();
        __builtin_amdgcn_sched_barrier(0);

        if (it + 4 < nt) stage(it + 4);

        const ushort* Ab = &As[(it % NBUF) * TBUF];
        const ushort* Bb = &Bs[(it % NBUF) * TBUF];
        short8 af[4], bfr[4];
#pragma unroll
        for (int m = 0; m < 4; ++m) af[m] = *(const short8*)&Ab[roA[m]];
#pragma unroll
        for (int n = 0; n < 4; ++n) bfr[n] = *(const short8*)&Bb[roB[n]];
        __builtin_amdgcn_s_setprio(1);
#pragma unroll
        for (int m = 0; m < 4; ++m)
#pragma unroll
            for (int n = 0; n < 4; ++n)
                acc[m][n] = __builtin_amdgcn_mfma_f32_16x16x32_bf16(af[m], bfr[n], acc[m][n], 0, 0, 0);
        __builtin_amdgcn_s_setprio(0);
    }

#pragma unroll
    for (int m = 0; m < 4; ++m) {
#pragma unroll
        for (int i = 0; i < 4; ++i) {
            const int row = bm + wr + m * 16 + g * 4 + i;
            if (row >= M) continue;
#pragma unroll
            for (int n = 0; n < 4; ++n) {
                const int col = bn + wc + n * 16 + lr;
                C[(size_t)row * ldc + col] = f2bf(acc[m][n][i]);
            }
        }
    }
}

// ---------------- fused gather-aggregate + combine, F=256 ----------------
// eidx shfl-preload + PREDICATED batches of 8: loads always issued 8-deep
// (clamped index), accumulate masked -> no serial tail for deg<8 nodes
// (45% of nodes; tail was 1 dependent ~500cy L3 gather per edge).
__global__ void k_gac256(const ushort* __restrict__ C, const int* __restrict__ rowptr,
                         const int* __restrict__ eidx, const float* __restrict__ bias,
                         ushort* __restrict__ hout) {
    int gid = blockIdx.x * blockDim.x + threadIdx.x;
    int node = gid >> 6;
    if (node >= NODES) return;
    const int lane = gid & 63;
    const int l4 = lane << 2;
    const int beg = rowptr[node];
    const int end = rowptr[node + 1];
    const int cnt = end - beg;
    const int pre = min(cnt, 64);
    int myeid = (lane < pre) ? eidx[beg + lane] : 0;

    float a0 = 0.f, a1 = 0.f, a2 = 0.f, a3 = 0.f;
    for (int i = 0; i < pre; i += 8) {
#pragma unroll
        for (int j = 0; j < 8; ++j) {
            const int ij = i + j;
            const bool ok = ij < pre;
            const int s = __shfl(myeid, ok ? ij : 0);
            const ushort4 v = *(const ushort4*)&C[(size_t)s * 512 + 256 + l4];
            if (ok) {
                a0 += bf2f(v.x); a1 += bf2f(v.y);
                a2 += bf2f(v.z); a3 += bf2f(v.w);
            }
        }
    }
    for (int e = beg + 64; e < end; ++e) {       // deg > 64 fallback (rare)
        int s = eidx[e];
        const ushort4 v = *(const ushort4*)&C[(size_t)s * 512 + 256 + l4];
        a0 += bf2f(v.x); a1 += bf2f(v.y); a2 += bf2f(v.z); a3 += bf2f(v.w);
    }
    const float inv = 1.f / (float)max(cnt, 1);
    const ushort4 hs = *(const ushort4*)&C[(size_t)node * 512 + l4];
    const f32x4 bv = *(const f32x4*)&bias[l4];
    ushort4 w;
    w.x = f2bf(fmaxf(bf2f(hs.x) + a0 * inv + bv[0], 0.f));
    w.y = f2bf(fmaxf(bf2f(hs.y) + a1 * inv + bv[1], 0.f));
    w.z = f2bf(fmaxf(bf2f(hs.z) + a2 * inv + bv[2], 0.f));
    w.w = f2bf(fmaxf(bf2f(hs.w) + a3 * inv + bv[3], 0.f));
    *(ushort4*)&hout[(size_t)node * 256 + l4] = w;   // LINEAR (GEMM swizzles at source)
}

// ---------------- final layer gather, F=47: 2 nodes/wave, predicated batches of 8 ----------------
__global__ void k_gac47(const ushort* __restrict__ C, const int* __restrict__ rowptr,
                        const int* __restrict__ eidx, const float* __restrict__ bias,
                        float* __restrict__ out) {
    int gid = blockIdx.x * blockDim.x + threadIdx.x;
    int wv = gid >> 6;
    const int lane = gid & 63;
    const int sub = lane >> 5, l = lane & 31;
    int node = wv * 2 + sub;
    if (node >= NODES) return;
    const uint32_t* C32 = (const uint32_t*)C;   // row stride 64 u32
    const int beg = rowptr[node];
    const int end = rowptr[node + 1];
    const int cnt = end - beg;
    const int pre = min(cnt, 32);
    int myeid = (l < pre) ? eidx[beg + l] : 0;

    float a0 = 0.f, a1 = 0.f;
    if (l < 24) {
        for (int i = 0; i < pre; i += 8) {
#pragma unroll
            for (int j = 0; j < 8; ++j) {
                const int ij = i + j;
                const bool ok = ij < pre;
                const int s = __shfl(myeid, ok ? ij : 0, 32);
                const uint32_t u = C32[(size_t)s * 64 + 32 + l];
                if (ok) {
                    a0 += bf2f((ushort)u);
                    a1 += bf2f((ushort)(u >> 16));
                }
            }
        }
        for (int e = beg + 32; e < end; ++e) {
            const uint32_t u = C32[(size_t)eidx[e] * 64 + 32 + l];
            a0 += bf2f((ushort)u);
            a1 += bf2f((ushort)(u >> 16));
        }
        const float inv = 1.f / (float)max(cnt, 1);
        const uint32_t us = C32[(size_t)node * 64 + l];
        const int c0 = 2 * l, c1 = 2 * l + 1;
        out[(size_t)node * FC + c0] = bf2f((ushort)us) + a0 * inv + bias[c0];
        if (c1 < FC)
            out[(size_t)node * FC + c1] = bf2f((ushort)(us >> 16)) + a1 * inv + bias[c1];
    }
}

extern "C" void kernel_launch(void* const* d_in, const int* in_sizes, int n_in,
                              void* d_out, int out_size, void* d_ws, size_t ws_size,
                              hipStream_t stream) {
    const float* x       = (const float*)d_in[0];
    const int*   src     = (const int*)d_in[1];
    const int*   dst     = (const int*)d_in[2];
    const float* Wself0  = (const float*)d_in[3];
    const float* Wneigh0 = (const float*)d_in[4];
    const float* b0      = (const float*)d_in[5];
    const float* Wself1  = (const float*)d_in[6];
    const float* Wneigh1 = (const float*)d_in[7];
    const float* b1      = (const float*)d_in[8];
    const float* Wself2  = (const float*)d_in[9];
    const float* Wneigh2 = (const float*)d_in[10];
    const float* b2      = (const float*)d_in[11];
    float* out = (float*)d_out;

    char* w = (char*)d_ws;
    ushort* Cbuf = (ushort*)w;   w += (size_t)NODES * 512 * 2;   // 51.2 MB
    ushort* xbf  = (ushort*)w;   w += (size_t)NODES * KP * 2;    // 102.4 MB
    ushort* hbuf = xbf;          // aliases xbf: xbf dead once L0 GEMM completes
    ushort* Wt0  = (ushort*)w;   w += (size_t)W0E * 2;
    ushort* Wt1  = (ushort*)w;   w += (size_t)W1E * 2;
    ushort* Wt2  = (ushort*)w;   w += (size_t)W2E * 2;
    int* rowptr  = (int*)w;      w += (NODES + 1) * sizeof(int);
    int* cursor  = (int*)w;      w += NODES * sizeof(int);
    int* degarr  = (int*)w;      w += NODES * sizeof(int);
    int* bsum    = (int*)w;      w += 256 * sizeof(int);
    int* eidx    = (int*)w;

    dim3 blk(256);

    // ---- CSR build + conversions (independent work co-launched) ----
    k_zero<<<SCAN_BLKS, blk, 0, stream>>>(degarr, NODES);
    k_cvtx_deg<<<CVTX_BLKS + DEG_BLKS, blk, 0, stream>>>(x, xbf, dst, degarr);
    k_scan1_cvtw0<<<SCAN_BLKS + CVTW0_BLKS, blk, 0, stream>>>(
        degarr, bsum, NODES, Wself0, Wneigh0, Wt0);
    k_scan2<<<1, blk, 0, stream>>>(bsum, SCAN_BLKS);
    k_scan3<<<SCAN_BLKS, blk, 0, stream>>>(degarr, bsum, rowptr, cursor, NODES);

    const int gat_blocks   = (int)(((size_t)NODES * 64 + 255) / 256);
    const int gat47_blocks = (int)((((size_t)NODES + 1) / 2 * 64 + 255) / 256);
    const int nbyM2 = (NODES + 255) / 256;      // 196
    const int nbyM  = (NODES + BMT - 1) / BMT;  // 391

    // ---- Layer 0 GEMM (+ eidx fill + Wt1/Wt2 convert in its prologue) ----
    k_mm256<1><<<dim3(2 * nbyM2), dim3(512), 0, stream>>>(
        xbf, Wt0, Cbuf, NODES, KP, KP, 512, 2,
        src, dst, cursor, eidx, Wself1, Wneigh1, Wself2, Wneigh2, Wt1, Wt2);
    k_gac256<<<gat_blocks, blk, 0, stream>>>(Cbuf, rowptr, eidx, b0, hbuf);

    // ---- Layer 1: C1 = h1 @ [Wself1|Wneigh1]  (K=256) ----
    k_mm256<0><<<dim3(2 * nbyM2), dim3(512), 0, stream>>>(
        hbuf, Wt1, Cbuf, NODES, FH, FH, 512, 2,
        nullptr, nullptr, nullptr, nullptr, nullptr, nullptr, nullptr, nullptr,
        nullptr, nullptr);
    k_gac256<<<gat_blocks, blk, 0, stream>>>(Cbuf, rowptr, eidx, b1, hbuf);

    // ---- Layer 2: C2 = h2 @ [Wself2|Wneigh2 padded]  (N=128, K=256) ----
    k_mm<<<dim3(nbyM), blk, 0, stream>>>(hbuf, Wt2, Cbuf, NODES, FH, FH, 128, 1);
    k_gac47<<<gat47_blocks, blk, 0, stream>>>(Cbuf, rowptr, eidx, b2, out);
}

// Round 19
// 298.284 us; speedup vs baseline: 1.0289x; 1.0289x over previous
//
#include <hip/hip_runtime.h>
#include <hip/hip_bf16.h>
#include <cstdint>

#define NODES 50000
#define EDGES 400000
#define FIN   988
#define KP    1024     // FIN padded to multiple of 64
#define FH    256
#define FC    47

typedef __attribute__((ext_vector_type(8))) short short8;
typedef __attribute__((ext_vector_type(4))) float f32x4;

__device__ __forceinline__ ushort f2bf(float x) {      // RNE f32 -> bf16
    union { float f; uint32_t u; } v; v.f = x;
    uint32_t r = v.u + 0x7FFF + ((v.u >> 16) & 1);
    return (ushort)(r >> 16);
}
__device__ __forceinline__ float bf2f(ushort u) {
    union { uint32_t u; float f; } v; v.u = ((uint32_t)u) << 16;
    return v.f;
}
__device__ __forceinline__ void g2l16(const void* g, void* l) {
    __builtin_amdgcn_global_load_lds((const __attribute__((address_space(1))) void*)g,
                                     (__attribute__((address_space(3))) void*)l, 16, 0, 0);
}

// ---------------- CSR build (parallel) ----------------
__global__ void k_zero(int* __restrict__ p, int n) {
    int i = blockIdx.x * blockDim.x + threadIdx.x;
    if (i < n) p[i] = 0;
}

// fused: blocks [0, CVTX_BLKS) convert x->xbf (BW-bound);
//        blocks [CVTX_BLKS, ..) count degrees (atomic-bound). Disjoint writes.
#define CVTX_BLKS (NODES * (KP / 8) / 256)          // 25000
#define DEG_BLKS  ((EDGES + 255) / 256)             // 1563
__global__ void k_cvtx_deg(const float* __restrict__ x, ushort* __restrict__ xbf,
                           const int* __restrict__ dst, int* __restrict__ deg) {
    const int b = blockIdx.x;
    if (b < CVTX_BLKS) {
        int gid = b * 256 + threadIdx.x;
        const int r  = gid >> 7;            // KP/8 = 128
        const int kb = (gid & 127) << 3;
        const float* p = x + (size_t)r * FIN + kb;
        short8 o;
        if (kb + 8 <= FIN) {
            f32x4 v0 = *(const f32x4*)(p);
            f32x4 v1 = *(const f32x4*)(p + 4);
#pragma unroll
            for (int i = 0; i < 4; ++i) {
                o[i] = (short)f2bf(v0[i]);
                o[4 + i] = (short)f2bf(v1[i]);
            }
        } else {
#pragma unroll
            for (int i = 0; i < 8; ++i) {
                float f = (kb + i < FIN) ? p[i] : 0.f;
                o[i] = (short)f2bf(f);
            }
        }
        *(short8*)&xbf[(size_t)r * KP + kb] = o;
    } else {
        int i = (b - CVTX_BLKS) * 256 + threadIdx.x;
        if (i < EDGES) atomicAdd(&deg[dst[i]], 1);
    }
}

// pass 1: per-block (256 elems) total -> bsum[bid]
__global__ __launch_bounds__(256) void k_scan1(const int* __restrict__ deg,
                                               int* __restrict__ bsum, int n) {
    __shared__ int ws[4];
    int i = blockIdx.x * 256 + threadIdx.x;
    int v = (i < n) ? deg[i] : 0;
#pragma unroll
    for (int off = 32; off; off >>= 1) v += __shfl_down(v, off);
    if ((threadIdx.x & 63) == 0) ws[threadIdx.x >> 6] = v;
    __syncthreads();
    if (threadIdx.x == 0) bsum[blockIdx.x] = ws[0] + ws[1] + ws[2] + ws[3];
}

// pass 2: exclusive scan of bsum[nb] in one block (nb <= 256)
__global__ __launch_bounds__(256) void k_scan2(int* __restrict__ bsum, int nb) {
    __shared__ int s[256];
    int t = threadIdx.x;
    int v = (t < nb) ? bsum[t] : 0;
    s[t] = v;
    __syncthreads();
    for (int off = 1; off < 256; off <<= 1) {
        int u = (t >= off) ? s[t - off] : 0;
        __syncthreads();
        s[t] += u;
        __syncthreads();
    }
    if (t < nb) bsum[t] = s[t] - v;   // exclusive prefix
}

// pass 3: rowptr[i] = bsum[bid] + in-block exclusive scan; cursor[i] = same
__global__ __launch_bounds__(256) void k_scan3(const int* __restrict__ deg,
                                               const int* __restrict__ bsum,
                                               int* __restrict__ rowptr,
                                               int* __restrict__ cursor, int n) {
    __shared__ int s[256];
    int t = threadIdx.x;
    int i = blockIdx.x * 256 + t;
    int v = (i < n) ? deg[i] : 0;
    s[t] = v;
    __syncthreads();
    for (int off = 1; off < 256; off <<= 1) {
        int u = (t >= off) ? s[t - off] : 0;
        __syncthreads();
        s[t] += u;
        __syncthreads();
    }
    if (i < n) {
        int excl = bsum[blockIdx.x] + s[t] - v;
        rowptr[i] = excl;
        cursor[i] = excl;
    }
    if (i == 0) rowptr[n] = EDGES;   // total degree == EDGES by construction
}

// fused: blocks [0, DEG_BLKS) bucket-fill eidx (atomic-bound);
//        blocks [DEG_BLKS, ..) weight transpose+convert (BW-bound). Disjoint.
#define W0E (512 * KP)
#define W1E (512 * FH)
#define W2E (128 * FH)
#define CVTW_BLKS ((W0E + W1E + W2E + 255) / 256)
__global__ void k_fill_cvtw(const int* __restrict__ src, const int* __restrict__ dst,
                            int* __restrict__ cursor, int* __restrict__ eidx,
                            const float* __restrict__ Ws0, const float* __restrict__ Wn0,
                            const float* __restrict__ Ws1, const float* __restrict__ Wn1,
                            const float* __restrict__ Ws2, const float* __restrict__ Wn2,
                            ushort* __restrict__ Wt0, ushort* __restrict__ Wt1,
                            ushort* __restrict__ Wt2) {
    const int b = blockIdx.x;
    if (b < DEG_BLKS) {
        int i = b * 256 + threadIdx.x;
        if (i < EDGES) {
            int d = dst[i];
            int p = atomicAdd(&cursor[d], 1);
            eidx[p] = src[i];
        }
    } else {
        int gid = (b - DEG_BLKS) * 256 + threadIdx.x;
        if (gid < W0E) {
            int k = gid >> 9, n = gid & 511;
            float v = 0.f;
            if (k < FIN) v = (n < FH) ? Ws0[(size_t)k * FH + n] : Wn0[(size_t)k * FH + (n - FH)];
            Wt0[(size_t)n * KP + k] = f2bf(v);
        } else if (gid < W0E + W1E) {
            int gg = gid - W0E;
            int k = gg >> 9, n = gg & 511;
            float v = (n < FH) ? Ws1[(size_t)k * FH + n] : Wn1[(size_t)k * FH + (n - FH)];
            Wt1[(size_t)n * FH + k] = f2bf(v);
        } else if (gid < W0E + W1E + W2E) {
            int gg = gid - W0E - W1E;
            int k = gg >> 7, n = gg & 127;
            float v = 0.f;
            if (n < FC) v = Ws2[(size_t)k * FC + n];
            else if (n >= 64 && n < 64 + FC) v = Wn2[(size_t)k * FC + (n - 64)];
            Wt2[(size_t)n * FH + k] = f2bf(v);
        }
    }
}

// ================= 256x256 bf16 GEMM, BK=64: 2-buffer counted-vmcnt double-buffer =================
#define TBK 16384   // ushorts per 256x64 tile buffer (32 KB)

__global__ __launch_bounds__(512, 2) void k_mm256(const ushort* __restrict__ A,
                                                  const ushort* __restrict__ Bt,
                                                  ushort* __restrict__ C,
                                                  const int M, const int lda,
                                                  const int Kpad, const int ldc,
                                                  const int nbx) {
    const int nwg = gridDim.x;
    const int bid = blockIdx.x;
    const int q = nwg >> 3, r = nwg & 7;
    const int xcd = bid & 7, ii = bid >> 3;
    const int swz = (xcd < r ? xcd * (q + 1) : r * (q + 1) + (xcd - r) * q) + ii;
    const int bm = (swz / nbx) * 256;
    const int bn = (swz % nbx) * 256;

    __shared__ ushort As[2 * TBK];   // 64 KB
    __shared__ ushort Bs[2 * TBK];   // 64 KB

    const int t = threadIdx.x;
    const int wid = t >> 6, lane = t & 63;
    const int wr = (wid >> 2) * 128, wc = (wid & 3) * 64;
    const int lr = lane & 15, g = lane >> 4;

    f32x4 acc[8][4] = {};

    const ushort* asrc[4]; const ushort* bsrc[4]; int cdst[4];
#pragma unroll
    for (int jj = 0; jj < 4; ++jj) {
        const int c = jj * 8 + wid;
        const int row = c * 8 + (lane >> 3);
        const int soff = ((lane & 7) ^ (row & 7)) << 3;   // source-side slot XOR
        const int arow = min(bm + row, M - 1);
        asrc[jj] = A + (size_t)arow * lda + soff;
        bsrc[jj] = Bt + (size_t)(bn + row) * Kpad + soff;
        cdst[jj] = c * 512;
    }

    int roA[2][8], roB[2][4];
#pragma unroll
    for (int m = 0; m < 8; ++m) {
        const int rr = wr + m * 16 + lr;
#pragma unroll
        for (int h = 0; h < 2; ++h)
            roA[h][m] = rr * 64 + ((((h << 2) + g) ^ (rr & 7)) << 3);
    }
#pragma unroll
    for (int n = 0; n < 4; ++n) {
        const int col = wc + n * 16 + lr;
#pragma unroll
        for (int h = 0; h < 2; ++h)
            roB[h][n] = col * 64 + ((((h << 2) + g) ^ (col & 7)) << 3);
    }

    auto stage = [&](int tile) {
        const int k0 = tile * 64;
        const int ho = (tile & 1) * TBK;
#pragma unroll
        for (int jj = 0; jj < 4; ++jj) g2l16(asrc[jj] + k0, &As[ho + cdst[jj]]);
#pragma unroll
        for (int jj = 0; jj < 4; ++jj) g2l16(bsrc[jj] + k0, &Bs[ho + cdst[jj]]);
    };

    const int nt = Kpad / 64;
    stage(0);
    if (nt > 1) stage(1);

    for (int it = 0; it < nt; ++it) {
        if (it + 1 < nt) asm volatile("s_waitcnt vmcnt(8)" ::: "memory");
        else             asm volatile("s_waitcnt vmcnt(0)" ::: "memory");
        __builtin_amdgcn_s_barrier();           // barrier-1: tile `it` resident
        __builtin_amdgcn_sched_barrier(0);

        const ushort* Ab = &As[(it & 1) * TBK];
        const ushort* Bb = &Bs[(it & 1) * TBK];
        short8 a0[8], b0[4], a1[8], b1[4];
#pragma unroll
        for (int m = 0; m < 8; ++m) a0[m] = *(const short8*)&Ab[roA[0][m]];
#pragma unroll
        for (int n = 0; n < 4; ++n) b0[n] = *(const short8*)&Bb[roB[0][n]];
#pragma unroll
        for (int m = 0; m < 8; ++m) a1[m] = *(const short8*)&Ab[roA[1][m]];
#pragma unroll
        for (int n = 0; n < 4; ++n) b1[n] = *(const short8*)&Bb[roB[1][n]];

        __builtin_amdgcn_s_setprio(1);
#pragma unroll
        for (int m = 0; m < 8; ++m)
#pragma unroll
            for (int n = 0; n < 4; ++n)
                acc[m][n] = __builtin_amdgcn_mfma_f32_16x16x32_bf16(a0[m], b0[n], acc[m][n], 0, 0, 0);
        __builtin_amdgcn_s_setprio(0);

        asm volatile("s_waitcnt lgkmcnt(0)" ::: "memory");
        __builtin_amdgcn_sched_barrier(0);
        __builtin_amdgcn_s_barrier();           // barrier-2: buf[it&1] reads done
        __builtin_amdgcn_sched_barrier(0);

        if (it + 2 < nt) stage(it + 2);         // overwrite buf[it&1] under MFMA h1

        __builtin_amdgcn_s_setprio(1);
#pragma unroll
        for (int m = 0; m < 8; ++m)
#pragma unroll
            for (int n = 0; n < 4; ++n)
                acc[m][n] = __builtin_amdgcn_mfma_f32_16x16x32_bf16(a1[m], b1[n], acc[m][n], 0, 0, 0);
        __builtin_amdgcn_s_setprio(0);
    }

#pragma unroll
    for (int m = 0; m < 8; ++m) {
#pragma unroll
        for (int i = 0; i < 4; ++i) {
            const int row = bm + wr + m * 16 + g * 4 + i;
            if (row >= M) continue;
#pragma unroll
            for (int n = 0; n < 4; ++n) {
                const int col = bn + wc + n * 16 + lr;
                C[(size_t)row * ldc + col] = f2bf(acc[m][n][i]);
            }
        }
    }
}

// ================= 128x128 bf16 GEMM — L2 (N=128), BK=32, linear sources =================
#define BMT 128
#define TBUF 4096
#define NBUF 5

__global__ __launch_bounds__(256, 4) void k_mm(const ushort* __restrict__ A,
                                               const ushort* __restrict__ Bt,
                                               ushort* __restrict__ C,
                                               const int M, const int lda,
                                               const int Kpad, const int ldc,
                                               const int nbx) {
    const int nwg = gridDim.x;
    const int bid = blockIdx.x;
    const int q = nwg >> 3, r = nwg & 7;
    const int xcd = bid & 7, ii = bid >> 3;
    const int swz = (xcd < r ? xcd * (q + 1) : r * (q + 1) + (xcd - r) * q) + ii;
    const int bm = (swz / nbx) * BMT;
    const int bn = (swz % nbx) * BMT;

    __shared__ ushort As[NBUF * TBUF];
    __shared__ ushort Bs[NBUF * TBUF];

    const int t = threadIdx.x;
    const int wid = t >> 6, lane = t & 63;
    const int wr = (wid >> 1) * 64, wc = (wid & 1) * 64;
    const int lr = lane & 15, g = lane >> 4;

    f32x4 acc[4][4] = {};

    const ushort* asrc[2]; const ushort* bsrc[2]; int cdst[2];
#pragma unroll
    for (int j = 0; j < 2; ++j) {
        const int c = j * 4 + wid;
        const int row = c * 16 + (lane >> 2);
        const int soff = (((lane & 3) ^ ((row >> 1) & 3)) << 3);  // source-side XOR
        const int arow = min(bm + row, M - 1);
        asrc[j] = A + (size_t)arow * lda + soff;
        bsrc[j] = Bt + (size_t)(bn + row) * Kpad + soff;
        cdst[j] = c * 512;
    }

    int roA[4], roB[4];
#pragma unroll
    for (int m = 0; m < 4; ++m) {
        const int row = wr + m * 16 + lr;
        roA[m] = row * 32 + ((g ^ ((row >> 1) & 3)) << 3);
    }
#pragma unroll
    for (int n = 0; n < 4; ++n) {
        const int col = wc + n * 16 + lr;
        roB[n] = col * 32 + ((g ^ ((col >> 1) & 3)) << 3);
    }

    auto stage = [&](int tile) {
        const int k0 = tile * 32;
        const int ho = (tile % NBUF) * TBUF;
        g2l16(asrc[0] + k0, &As[ho + cdst[0]]);
        g2l16(asrc[1] + k0, &As[ho + cdst[1]]);
        g2l16(bsrc[0] + k0, &Bs[ho + cdst[0]]);
        g2l16(bsrc[1] + k0, &Bs[ho + cdst[1]]);
    };

    const int nt = Kpad / 32;
#pragma unroll
    for (int p = 0; p < 4; ++p) if (p < nt) stage(p);

    for (int it = 0; it < nt; ++it) {
        const int rmn = nt - 1 - it;
        if (rmn >= 3)      asm volatile("s_waitcnt vmcnt(12)" ::: "memory");
        else if (rmn == 2) asm volatile("s_waitcnt vmcnt(8)"  ::: "memory");
        else if (rmn == 1) asm volatile("s_waitcnt vmcnt(4)"  ::: "memory");
        else               asm volatile("s_waitcnt vmcnt(0)"  ::: "memory");
        __builtin_amdgcn_s_barrier();
        __builtin_amdgcn_sched_barrier(0);

        if (it + 4 < nt) stage(it + 4);

        const ushort* Ab = &As[(it % NBUF) * TBUF];
        const ushort* Bb = &Bs[(it % NBUF) * TBUF];
        short8 af[4], bfr[4];
#pragma unroll
        for (int m = 0; m < 4; ++m) af[m] = *(const short8*)&Ab[roA[m]];
#pragma unroll
        for (int n = 0; n < 4; ++n) bfr[n] = *(const short8*)&Bb[roB[n]];
        __builtin_amdgcn_s_setprio(1);
#pragma unroll
        for (int m = 0; m < 4; ++m)
#pragma unroll
            for (int n = 0; n < 4; ++n)
                acc[m][n] = __builtin_amdgcn_mfma_f32_16x16x32_bf16(af[m], bfr[n], acc[m][n], 0, 0, 0);
        __builtin_amdgcn_s_setprio(0);
    }

#pragma unroll
    for (int m = 0; m < 4; ++m) {
#pragma unroll
        for (int i = 0; i < 4; ++i) {
            const int row = bm + wr + m * 16 + g * 4 + i;
            if (row >= M) continue;
#pragma unroll
            for (int n = 0; n < 4; ++n) {
                const int col = bn + wc + n * 16 + lr;
                C[(size_t)row * ldc + col] = f2bf(acc[m][n][i]);
            }
        }
    }
}

// ---------------- fused gather-aggregate + combine, F=256 (eidx shfl-preload) ----------------
// self-row + bias loads hoisted ABOVE the gather loop (overlap with gathers).
__global__ void k_gac256(const ushort* __restrict__ C, const int* __restrict__ rowptr,
                         const int* __restrict__ eidx, const float* __restrict__ bias,
                         ushort* __restrict__ hout) {
    int gid = blockIdx.x * blockDim.x + threadIdx.x;
    int node = gid >> 6;
    if (node >= NODES) return;
    const int lane = gid & 63;
    const int l4 = lane << 2;
    const int beg = rowptr[node];
    const int end = rowptr[node + 1];
    const int cnt = end - beg;
    const int pre = min(cnt, 64);
    int myeid = (lane < pre) ? eidx[beg + lane] : 0;
    const ushort4 hs = *(const ushort4*)&C[(size_t)node * 512 + l4];   // hoisted
    const f32x4 bv = *(const f32x4*)&bias[l4];                         // hoisted

    float a0 = 0.f, a1 = 0.f, a2 = 0.f, a3 = 0.f;
    int i = 0;
    for (; i + 7 < pre; i += 8) {
        int s0 = __shfl(myeid, i),     s1 = __shfl(myeid, i + 1);
        int s2 = __shfl(myeid, i + 2), s3 = __shfl(myeid, i + 3);
        int s4 = __shfl(myeid, i + 4), s5 = __shfl(myeid, i + 5);
        int s6 = __shfl(myeid, i + 6), s7 = __shfl(myeid, i + 7);
        const ushort4 v0 = *(const ushort4*)&C[(size_t)s0 * 512 + 256 + l4];
        const ushort4 v1 = *(const ushort4*)&C[(size_t)s1 * 512 + 256 + l4];
        const ushort4 v2 = *(const ushort4*)&C[(size_t)s2 * 512 + 256 + l4];
        const ushort4 v3 = *(const ushort4*)&C[(size_t)s3 * 512 + 256 + l4];
        const ushort4 v4 = *(const ushort4*)&C[(size_t)s4 * 512 + 256 + l4];
        const ushort4 v5 = *(const ushort4*)&C[(size_t)s5 * 512 + 256 + l4];
        const ushort4 v6 = *(const ushort4*)&C[(size_t)s6 * 512 + 256 + l4];
        const ushort4 v7 = *(const ushort4*)&C[(size_t)s7 * 512 + 256 + l4];
        a0 += ((bf2f(v0.x) + bf2f(v1.x)) + (bf2f(v2.x) + bf2f(v3.x)))
            + ((bf2f(v4.x) + bf2f(v5.x)) + (bf2f(v6.x) + bf2f(v7.x)));
        a1 += ((bf2f(v0.y) + bf2f(v1.y)) + (bf2f(v2.y) + bf2f(v3.y)))
            + ((bf2f(v4.y) + bf2f(v5.y)) + (bf2f(v6.y) + bf2f(v7.y)));
        a2 += ((bf2f(v0.z) + bf2f(v1.z)) + (bf2f(v2.z) + bf2f(v3.z)))
            + ((bf2f(v4.z) + bf2f(v5.z)) + (bf2f(v6.z) + bf2f(v7.z)));
        a3 += ((bf2f(v0.w) + bf2f(v1.w)) + (bf2f(v2.w) + bf2f(v3.w)))
            + ((bf2f(v4.w) + bf2f(v5.w)) + (bf2f(v6.w) + bf2f(v7.w)));
    }
    for (; i < pre; ++i) {
        int s = __shfl(myeid, i);
        const ushort4 v = *(const ushort4*)&C[(size_t)s * 512 + 256 + l4];
        a0 += bf2f(v.x); a1 += bf2f(v.y); a2 += bf2f(v.z); a3 += bf2f(v.w);
    }
    for (int e = beg + 64; e < end; ++e) {
        int s = eidx[e];
        const ushort4 v = *(const ushort4*)&C[(size_t)s * 512 + 256 + l4];
        a0 += bf2f(v.x); a1 += bf2f(v.y); a2 += bf2f(v.z); a3 += bf2f(v.w);
    }
    const float inv = 1.f / (float)max(cnt, 1);
    ushort4 w;
    w.x = f2bf(fmaxf(bf2f(hs.x) + a0 * inv + bv[0], 0.f));
    w.y = f2bf(fmaxf(bf2f(hs.y) + a1 * inv + bv[1], 0.f));
    w.z = f2bf(fmaxf(bf2f(hs.z) + a2 * inv + bv[2], 0.f));
    w.w = f2bf(fmaxf(bf2f(hs.w) + a3 * inv + bv[3], 0.f));
    *(ushort4*)&hout[(size_t)node * 256 + l4] = w;   // LINEAR (GEMM swizzles at source)
}

// ---------------- final layer gather, F=47: 2 nodes/wave, u32 loads, eidx preload ----------------
__global__ void k_gac47(const ushort* __restrict__ C, const int* __restrict__ rowptr,
                        const int* __restrict__ eidx, const float* __restrict__ bias,
                        float* __restrict__ out) {
    int gid = blockIdx.x * blockDim.x + threadIdx.x;
    int wv = gid >> 6;
    const int lane = gid & 63;
    const int sub = lane >> 5, l = lane & 31;
    int node = wv * 2 + sub;
    if (node >= NODES) return;
    const uint32_t* C32 = (const uint32_t*)C;   // row stride 64 u32
    const int beg = rowptr[node];
    const int end = rowptr[node + 1];
    const int cnt = end - beg;
    const int pre = min(cnt, 32);
    int myeid = (l < pre) ? eidx[beg + l] : 0;

    float a0 = 0.f, a1 = 0.f;
    if (l < 24) {
        const uint32_t us = C32[(size_t)node * 64 + l];   // hoisted self load
        int i = 0;
        for (; i + 3 < pre; i += 4) {
            int s0 = __shfl(myeid, i,     32);
            int s1 = __shfl(myeid, i + 1, 32);
            int s2 = __shfl(myeid, i + 2, 32);
            int s3 = __shfl(myeid, i + 3, 32);
            const uint32_t u0 = C32[(size_t)s0 * 64 + 32 + l];
            const uint32_t u1 = C32[(size_t)s1 * 64 + 32 + l];
            const uint32_t u2 = C32[(size_t)s2 * 64 + 32 + l];
            const uint32_t u3 = C32[(size_t)s3 * 64 + 32 + l];
            a0 += (bf2f((ushort)u0) + bf2f((ushort)u1)) + (bf2f((ushort)u2) + bf2f((ushort)u3));
            a1 += (bf2f((ushort)(u0 >> 16)) + bf2f((ushort)(u1 >> 16)))
                + (bf2f((ushort)(u2 >> 16)) + bf2f((ushort)(u3 >> 16)));
        }
        for (; i < pre; ++i) {
            int s = __shfl(myeid, i, 32);
            const uint32_t u = C32[(size_t)s * 64 + 32 + l];
            a0 += bf2f((ushort)u);
            a1 += bf2f((ushort)(u >> 16));
        }
        for (int e = beg + 32; e < end; ++e) {
            const uint32_t u = C32[(size_t)eidx[e] * 64 + 32 + l];
            a0 += bf2f((ushort)u);
            a1 += bf2f((ushort)(u >> 16));
        }
        const float inv = 1.f / (float)max(cnt, 1);
        const int c0 = 2 * l, c1 = 2 * l + 1;
        out[(size_t)node * FC + c0] = bf2f((ushort)us) + a0 * inv + bias[c0];
        if (c1 < FC)
            out[(size_t)node * FC + c1] = bf2f((ushort)(us >> 16)) + a1 * inv + bias[c1];
    }
}

extern "C" void kernel_launch(void* const* d_in, const int* in_sizes, int n_in,
                              void* d_out, int out_size, void* d_ws, size_t ws_size,
                              hipStream_t stream) {
    const float* x       = (const float*)d_in[0];
    const int*   src     = (const int*)d_in[1];
    const int*   dst     = (const int*)d_in[2];
    const float* Wself0  = (const float*)d_in[3];
    const float* Wneigh0 = (const float*)d_in[4];
    const float* b0      = (const float*)d_in[5];
    const float* Wself1  = (const float*)d_in[6];
    const float* Wneigh1 = (const float*)d_in[7];
    const float* b1      = (const float*)d_in[8];
    const float* Wself2  = (const float*)d_in[9];
    const float* Wneigh2 = (const float*)d_in[10];
    const float* b2      = (const float*)d_in[11];
    float* out = (float*)d_out;

    char* w = (char*)d_ws;
    ushort* Cbuf = (ushort*)w;   w += (size_t)NODES * 512 * 2;   // 51.2 MB
    ushort* xbf  = (ushort*)w;   w += (size_t)NODES * KP * 2;    // 102.4 MB
    ushort* hbuf = xbf;          // aliases xbf: xbf dead once L0 GEMM completes
    ushort* Wt0  = (ushort*)w;   w += (size_t)W0E * 2;
    ushort* Wt1  = (ushort*)w;   w += (size_t)W1E * 2;
    ushort* Wt2  = (ushort*)w;   w += (size_t)W2E * 2;
    int* rowptr  = (int*)w;      w += (NODES + 1) * sizeof(int);
    int* cursor  = (int*)w;      w += NODES * sizeof(int);
    int* degarr  = (int*)w;      w += NODES * sizeof(int);
    int* bsum    = (int*)w;      w += 256 * sizeof(int);
    int* eidx    = (int*)w;

    dim3 blk(256);
    const int nblk = (NODES + 255) / 256;   // 196

    // ---- CSR build + conversions (independent work co-launched) ----
    k_zero<<<nblk, blk, 0, stream>>>(degarr, NODES);
    k_cvtx_deg<<<CVTX_BLKS + DEG_BLKS, blk, 0, stream>>>(x, xbf, dst, degarr);
    k_scan1<<<nblk, blk, 0, stream>>>(degarr, bsum, NODES);
    k_scan2<<<1, blk, 0, stream>>>(bsum, nblk);
    k_scan3<<<nblk, blk, 0, stream>>>(degarr, bsum, rowptr, cursor, NODES);
    k_fill_cvtw<<<DEG_BLKS + CVTW_BLKS, blk, 0, stream>>>(
        src, dst, cursor, eidx,
        Wself0, Wneigh0, Wself1, Wneigh1, Wself2, Wneigh2, Wt0, Wt1, Wt2);

    const int gat_blocks   = (int)(((size_t)NODES * 64 + 255) / 256);
    const int gat47_blocks = (int)((((size_t)NODES + 1) / 2 * 64 + 255) / 256);
    const int nbyM2 = (NODES + 255) / 256;      // 196
    const int nbyM  = (NODES + BMT - 1) / BMT;  // 391

    // ---- Layer 0: C0 = xbf @ [Wself0|Wneigh0]  (M=50000, N=512, K=1024) ----
    k_mm256<<<dim3(2 * nbyM2), dim3(512), 0, stream>>>(xbf, Wt0, Cbuf, NODES, KP, KP, 512, 2);
    k_gac256<<<gat_blocks, blk, 0, stream>>>(Cbuf, rowptr, eidx, b0, hbuf);

    // ---- Layer 1: C1 = h1 @ [Wself1|Wneigh1]  (K=256) ----
    k_mm256<<<dim3(2 * nbyM2), dim3(512), 0, stream>>>(hbuf, Wt1, Cbuf, NODES, FH, FH, 512, 2);
    k_gac256<<<gat_blocks, blk, 0, stream>>>(Cbuf, rowptr, eidx, b1, hbuf);

    // ---- Layer 2: C2 = h2 @ [Wself2|Wneigh2 padded]  (N=128, K=256) ----
    k_mm<<<dim3(nbyM), blk, 0, stream>>>(hbuf, Wt2, Cbuf, NODES, FH, FH, 128, 1);
    k_gac47<<<gat47_blocks, blk, 0, stream>>>(Cbuf, rowptr, eidx, b2, out);
}